// Round 8
// baseline (230.092 us; speedup 1.0000x reference)
//
#include <hip/hip_runtime.h>
#include <hip/hip_bf16.h>
#include <cstdint>

typedef __attribute__((ext_vector_type(8))) __bf16 bf8;
typedef __attribute__((ext_vector_type(4))) float f32x4;

// order-preserving float<->uint maps (for atomicMin/Max on sim values)
__device__ __forceinline__ unsigned mapf(float x){
  unsigned u = __float_as_uint(x);
  return (u & 0x80000000u) ? ~u : (u | 0x80000000u);
}
__device__ __forceinline__ float unmapf(unsigned u){
  return __uint_as_float((u & 0x80000000u) ? (u & 0x7FFFFFFFu) : ~u);
}

__device__ float digammaf_(float x){
  float r = 0.f;
  while (x < 6.f){ r -= 1.f/x; x += 1.f; }
  float inv = 1.f/x, inv2 = inv*inv;
  r += logf(x) - 0.5f*inv
     - inv2*(0.08333333333f - inv2*(0.008333333333f - inv2*0.003968253968f));
  return r;
}

// ============ k_prep: normalize -> TILED bf16 (fb2) + per-sample losses =====
// fb2 layout: panel p=row/64 (64 rows), chunk c=k/32; each chunk is 4KB
// CONTIGUOUS: elem (r=row%64, kk=k%32) at (p*16+c)*2048 + r*32 + cb'*8 + kk%8,
// cb' = (kk/8) ^ ((r>>1)&3).  Also zeroes the k_pairs completion counter.
__global__ __launch_bounds__(256) void k_prep(const float* __restrict__ feat,
    __bf16* __restrict__ fb2,
    const float* __restrict__ logits, const int* __restrict__ targets,
    const float* __restrict__ alpha,  const float* __restrict__ fa,
    const float* __restrict__ cw, int B, int D,
    float* __restrict__ psum, unsigned* rowMinU, unsigned* rowMaxU,
    unsigned* done){
  int bid = blockIdx.x, tid = threadIdx.x;
  int wave = tid >> 6, lane = tid & 63;
  __shared__ float sloc[4][8];

  if (bid == 0 && tid == 0) *done = 0u;

  int row = bid*4 + wave;                       // grid = B/4, always < B
  // ---- normalize one row per wave ----
  const float* src = feat + (size_t)row*D;
  float ss = 0.f;
  for (int c = lane*4; c < D; c += 64*4){
    float4 v = *(const float4*)(src + c);
    ss += v.x*v.x + v.y*v.y + v.z*v.z + v.w*v.w;
  }
  #pragma unroll
  for (int off=32; off; off>>=1) ss += __shfl_xor(ss, off);
  float inv = 1.f / fmaxf(sqrtf(ss), 1e-12f);

  int p = row >> 6, r = row & 63;
  int rsw = (r >> 1) & 3;
  for (int c = lane*8; c < D; c += 64*8){
    float4 v0 = *(const float4*)(src + c);
    float4 v1 = *(const float4*)(src + c + 4);
    bf8 o;
    o[0]=(__bf16)(v0.x*inv); o[1]=(__bf16)(v0.y*inv);
    o[2]=(__bf16)(v0.z*inv); o[3]=(__bf16)(v0.w*inv);
    o[4]=(__bf16)(v1.x*inv); o[5]=(__bf16)(v1.y*inv);
    o[6]=(__bf16)(v1.z*inv); o[7]=(__bf16)(v1.w*inv);
    int cc = c >> 5;                  // chunk
    int cb = (c >> 3) & 3;            // 8-elem group within chunk
    size_t off = (size_t)(p*16 + cc)*2048 + r*32 + ((cb ^ rsw)*8);
    *(bf8*)(fb2 + off) = o;
  }

  // ---- init row min/max (4 rows per block) ----
  if (tid < 4){ rowMinU[bid*4+tid] = 0xFFFFFFFFu; rowMaxU[bid*4+tid] = 0u; }

  // ---- per-sample losses: sample i = row (redundant across lanes) ----
  int i = row;
  float l0=logits[3*i], l1=logits[3*i+1], l2=logits[3*i+2];
  int t = targets[i];
  float m = fmaxf(l0, fmaxf(l1,l2));
  float e0=expf(l0-m), e1=expf(l1-m), e2=expf(l2-m);
  float se = e0+e1+e2;
  float lse = m + logf(se);
  float lp0=l0-lse, lp1=l1-lse, lp2=l2-lse;
  float lpt = (t==0)?lp0:((t==1)?lp1:lp2);
  float nll = -lpt;
  float ce_ls = 0.9f*nll + 0.1f*(-(lp0+lp1+lp2)*(1.f/3.f));
  float pt = expf(-ce_ls);
  float om = 1.f - pt;
  float focal_i = fa[t]*om*om*ce_ls;
  float w = cw[t];
  float ce_n = w*nll, ce_d = w;
  float p0=e0/se, p1=e1/se, p2=e2/se;
  float bnd;
  if (t==0)      bnd = p1 + 0.6f*p2;
  else if (t==2) bnd = p1 + 0.4f*p0;
  else           bnd = 4.5f*(1.f - p1 + 0.3f*(p0+p2));
  float a0=alpha[3*i], a1=alpha[3*i+1], a2=alpha[3*i+2];
  float S = a0+a1+a2 + 1e-8f;
  float at_ = (t==0)?a0:((t==1)?a1:a2);
  float lik = digammaf_(S) - digammaf_(at_ + 1e-8f);
  float b0 = (t==0)?1.f:a0, b1 = (t==1)?1.f:a1, b2 = (t==2)?1.f:a2;
  float ats = b0+b1+b2 + 1e-8f;
  float psa = digammaf_(ats + 1e-8f);
  float kl = lgammaf(ats)
     - (lgammaf(b0+1e-8f)+lgammaf(b1+1e-8f)+lgammaf(b2+1e-8f))
     + (b0-1.f)*(digammaf_(b0+1e-8f)-psa)
     + (b1-1.f)*(digammaf_(b1+1e-8f)-psa)
     + (b2-1.f)*(digammaf_(b2+1e-8f)-psa);
  if (lane == 0){
    sloc[wave][0]=focal_i; sloc[wave][1]=ce_n; sloc[wave][2]=ce_d;
    sloc[wave][3]=bnd;     sloc[wave][4]=lik;  sloc[wave][5]=kl;
  }
  __syncthreads();
  if (tid < 6)
    psum[bid*8+tid] = sloc[0][tid]+sloc[1][tid]+sloc[2][tid]+sloc[3][tid];
}

// ============ k_pairs: single-wave 64x64 tiles, NO LDS, direct VGPR loads ===
// 2080 blocks x 64 threads, triangular (by<=bx). Fragment reads go straight
// from the tiled fb2 to VGPRs: the fragment pattern is a bijection onto the
// 4KB chunk, so each wave-instruction reads 1KB contiguous (8 full lines).
// No barriers, no LDS -> pure global_load <-> MFMA pipeline w/ fine vmcnt.
// Last-finishing block runs the finalize (counter + threadfence handshake).
__global__ __launch_bounds__(64) void k_pairs(const __bf16* __restrict__ fb2,
    const int* __restrict__ targets, int B, int D,
    float* __restrict__ pairPart, unsigned* rowMinU, unsigned* rowMaxU,
    unsigned* done, int nblk, int nprep,
    const float* __restrict__ psum, const int* __restrict__ epoch_p,
    float* __restrict__ out){
  // decode triangular tile index -> (by, bx), by <= bx
  int t = blockIdx.x;
  int bx = (int)((sqrtf(8.f*(float)t + 1.f) - 1.f)*0.5f);
  while ((bx+1)*(bx+2)/2 <= t) bx++;
  while (bx*(bx+1)/2 > t) bx--;
  int by = t - bx*(bx+1)/2;
  bool isDiag = (by == bx);
  int rowBase = by*64, colBase = bx*64;

  int lane = threadIdx.x;
  int quad = lane >> 4, l16 = lane & 15;
  int NCH = D/32;                                   // 16 chunks per panel

  // fragment offsets within a chunk (elements), inverse of baked swizzle
  int offA[4];
  #pragma unroll
  for (int mi=0; mi<4; mi++){
    int R = mi*16 + l16;
    offA[mi] = R*32 + ((quad ^ ((R>>1)&3))*8);
  }
  const __bf16* pA[4]; const __bf16* pB[4];
  #pragma unroll
  for (int mi=0; mi<4; mi++){
    pA[mi] = fb2 + (size_t)by*NCH*2048 + offA[mi];
    pB[mi] = fb2 + (size_t)bx*NCH*2048 + offA[mi];
  }

  f32x4 C[4][4] = {};
  bf8 aC[4], bC[4], aN[4], bN[4];

  #define LD(dst, P, it) do{ \
    _Pragma("unroll") \
    for (int j=0; j<4; j++) dst[j] = *(const bf8*)(P[j] + (it)*2048); \
  }while(0)

  #define COMPUTE(aF, bF) do{ \
    _Pragma("unroll") \
    for (int mi=0; mi<4; mi++) \
      _Pragma("unroll") \
      for (int ni=0; ni<4; ni++) \
        C[mi][ni] = __builtin_amdgcn_mfma_f32_16x16x32_bf16(aF[mi], bF[ni], C[mi][ni], 0,0,0); \
  }while(0)

  LD(aC, pA, 0); LD(bC, pB, 0);
  for (int it=0; it<NCH; it+=2){
    LD(aN, pA, it+1); LD(bN, pB, it+1);
    COMPUTE(aC, bC);
    if (it+2 < NCH){ LD(aC, pA, it+2); LD(bC, pB, it+2); }
    COMPUTE(aN, bN);
  }

  // ---- fused epilogue (validated rounds 1-7, absmax 0) ----
  int tcol[4];
  #pragma unroll
  for (int ni=0; ni<4; ni++) tcol[ni] = targets[colBase + ni*16 + l16];

  float pos=0.f, neg=0.f, semi=0.f, diag=0.f;
  float cmin[4], cmax[4];
  #pragma unroll
  for (int ni=0; ni<4; ni++){ cmin[ni]=2.f; cmax[ni]=-2.f; }

  #pragma unroll
  for (int mi=0; mi<4; mi++){
    #pragma unroll
    for (int r=0; r<4; r++){
      int rl = mi*16 + quad*4 + r;
      int row = rowBase + rl;
      int tr = targets[row];
      float vmin = 2.f, vmax = -2.f;
      #pragma unroll
      for (int ni=0; ni<4; ni++){
        int col = colBase + ni*16 + l16;
        float s = C[mi][ni][r];
        if (tr == tcol[ni]){
          float omv = 1.f - s;
          float q = omv*omv;
          pos += q;
          if (tr == 1) semi += q;
          if (row == col) diag += q;     // only possible on diagonal tiles
          else {
            vmin = fminf(vmin, s);
            cmin[ni] = fminf(cmin[ni], s);
          }
        } else {
          float c0 = fmaxf(s - 0.2f, 0.f);
          neg += c0*c0;
          vmax = fmaxf(vmax, s);
          cmax[ni] = fmaxf(cmax[ni], s);
        }
      }
      #pragma unroll
      for (int off=1; off<16; off<<=1){
        vmin = fminf(vmin, __shfl_xor(vmin, off));
        vmax = fmaxf(vmax, __shfl_xor(vmax, off));
      }
      if (l16 == 0){
        atomicMin(&rowMinU[row], mapf(vmin));
        atomicMax(&rowMaxU[row], mapf(vmax));
      }
    }
  }

  if (!isDiag){
    #pragma unroll
    for (int ni=0; ni<4; ni++){
      float cn = cmin[ni], cx = cmax[ni];
      cn = fminf(cn, __shfl_xor(cn, 16)); cn = fminf(cn, __shfl_xor(cn, 32));
      cx = fmaxf(cx, __shfl_xor(cx, 16)); cx = fmaxf(cx, __shfl_xor(cx, 32));
      if (quad == 0){
        int col = colBase + ni*16 + l16;
        atomicMin(&rowMinU[col], mapf(cn));
        atomicMax(&rowMaxU[col], mapf(cx));
      }
    }
  }

  #pragma unroll
  for (int off=32; off; off>>=1){
    pos  += __shfl_xor(pos, off);
    neg  += __shfl_xor(neg, off);
    semi += __shfl_xor(semi, off);
    diag += __shfl_xor(diag, off);
  }
  if (lane == 0){
    float fac = isDiag ? 1.f : 2.f;
    pairPart[blockIdx.x*4+0] = pos*fac;
    pairPart[blockIdx.x*4+1] = neg*fac;
    pairPart[blockIdx.x*4+2] = semi*fac;
    pairPart[blockIdx.x*4+3] = diag;
  }

  // ---- last-block finalize (device-scope counter handshake) ----
  __threadfence();                       // release: our stores visible
  unsigned old = 0;
  if (lane == 0) old = atomicAdd(done, 1u);
  old = (unsigned)__shfl((int)old, 0);
  if (old != (unsigned)(nblk - 1)) return;
  __threadfence();                       // acquire: everyone's stores visible

  // histogram targets
  int c0=0,c1=0,c2=0;
  for (int i4 = lane; i4 < B/4; i4 += 64){
    int4 tv = ((const int4*)targets)[i4];
    c0 += (tv.x==0)+(tv.y==0)+(tv.z==0)+(tv.w==0);
    c1 += (tv.x==1)+(tv.y==1)+(tv.z==1)+(tv.w==1);
    c2 += (tv.x==2)+(tv.y==2)+(tv.z==2)+(tv.w==2);
  }
  #pragma unroll
  for (int off=32; off; off>>=1){
    c0+=__shfl_xor(c0,off); c1+=__shfl_xor(c1,off); c2+=__shfl_xor(c2,off);
  }
  int n0=c0, n1=c1, n2=c2;

  // per-sample partials
  float v0=0,v1=0,v2=0,v3=0,v4=0,v5=0;
  for (int s = lane; s < nprep; s += 64){
    float4 a = *(const float4*)(psum + s*8);
    float4 b = *(const float4*)(psum + s*8 + 4);
    v0+=a.x; v1+=a.y; v2+=a.z; v3+=a.w; v4+=b.x; v5+=b.y;
  }
  // pair partials
  float pp=0,nn=0,ss=0,dd=0;
  for (int s = lane; s < nblk; s += 64){
    float4 a = *(const float4*)(pairPart + s*4);
    pp+=a.x; nn+=a.y; ss+=a.z; dd+=a.w;
  }
  // triplet
  float tsum = 0.f, tcnt = 0.f;
  for (int i = lane; i < B; i += 64){
    int tt = targets[i];
    int nt = (tt==0)?n0:((tt==1)?n1:n2);
    if (nt - 1 > 0 && B - nt > 0){
      float mn = unmapf(rowMinU[i]);
      float mx = unmapf(rowMaxU[i]);
      float hp = sqrtf(fmaxf(2.f - 2.f*mn, 0.f));
      float hn = sqrtf(fmaxf(2.f - 2.f*mx, 0.f));
      float margin = 1.5f * ((tt==1) ? 2.5f : 1.f);
      tsum += fmaxf(hp - hn + margin, 0.f); tcnt += 1.f;
    }
  }
  #pragma unroll
  for (int off=32; off; off>>=1){
    v0+=__shfl_xor(v0,off); v1+=__shfl_xor(v1,off); v2+=__shfl_xor(v2,off);
    v3+=__shfl_xor(v3,off); v4+=__shfl_xor(v4,off); v5+=__shfl_xor(v5,off);
    pp+=__shfl_xor(pp,off); nn+=__shfl_xor(nn,off);
    ss+=__shfl_xor(ss,off); dd+=__shfl_xor(dd,off);
    tsum+=__shfl_xor(tsum,off); tcnt+=__shfl_xor(tcnt,off);
  }
  if (lane == 0){
    float triplet = (tcnt > 0.f) ? tsum / fmaxf(tcnt, 1.f) : 0.f;
    float Bf = (float)B;
    float focal = v0 / Bf;
    float ce = v1 / v2;
    float boundary = v3 / (Bf + 1e-8f);
    float contrastive = (pp + nn + 4.f*ss) / (Bf*Bf + 1e-8f);
    long long npl = ((long long)n0*(n0-1) + (long long)n1*(n1-1) + (long long)n2*(n2-1))/2;
    float qsum = (pp - dd) * 0.5f;
    float q = qsum / (float)(npl > 0 ? npl : 1);
    if (n2 > 0) q *= (1.f + 2.5f * ((float)n2 / Bf));
    float quality = (npl > 0) ? q : 0.f;
    int ep = epoch_p[0];
    float er = (float)ep / 25.f;
    float ann = fminf(1.f, er*er);
    float evidential = v4/Bf + ann*0.2f*v5/Bf;
    float total = 0.4f*focal + 0.3f*ce + 0.15f*boundary
                + 0.1f*contrastive + 0.1f*triplet + 0.1f*quality + 0.1f*evidential;
    out[0] = total;
  }
}

extern "C" void kernel_launch(void* const* d_in, const int* in_sizes, int n_in,
                              void* d_out, int out_size, void* d_ws, size_t ws_size,
                              hipStream_t stream){
  const float* logits   = (const float*)d_in[0];
  const int*   targets  = (const int*)d_in[1];
  const float* features = (const float*)d_in[2];
  const float* alpha    = (const float*)d_in[3];
  const int*   epoch    = (const int*)d_in[4];
  const float* fa       = (const float*)d_in[5];
  const float* cw       = (const float*)d_in[6];
  int B = in_sizes[1];
  int D = in_sizes[2] / B;
  int nprep = B/4;                 // k_prep blocks == psum slots
  int T  = B / 64;
  int nblk = T*(T+1)/2;            // triangular: by <= bx

  char* ws = (char*)d_ws;
  float*    psum     = (float*)(ws);                          // nprep*8 f32 (32KB)
  unsigned* done     = (unsigned*)(ws + 49152);               // 1 u32
  float*    pairPart = (float*)(ws + 65536);                  // nblk*4 f32 (~33KB)
  unsigned* rowMinU  = (unsigned*)(ws + 131072);              // B u32
  unsigned* rowMaxU  = (unsigned*)(ws + 131072 + (size_t)B*4);
  __bf16*   fb2      = (__bf16*)(ws + 131072 + (size_t)B*8);  // B*D bf16 tiled

  k_prep <<<nprep, 256, 0, stream>>>(features, fb2, logits, targets, alpha, fa, cw,
                                     B, D, psum, rowMinU, rowMaxU, done);
  k_pairs<<<nblk, 64, 0, stream>>>(fb2, targets, B, D, pairPart, rowMinU, rowMaxU,
                                   done, nblk, nprep, psum, epoch, (float*)d_out);
}

// Round 9
// 229.212 us; speedup vs baseline: 1.0038x; 1.0038x over previous
//
#include <hip/hip_runtime.h>
#include <hip/hip_bf16.h>
#include <cstdint>

typedef __attribute__((ext_vector_type(8))) __bf16 bf8;
typedef __attribute__((ext_vector_type(4))) float f32x4;

// order-preserving float<->uint maps (for atomicMin/Max on sim values)
__device__ __forceinline__ unsigned mapf(float x){
  unsigned u = __float_as_uint(x);
  return (u & 0x80000000u) ? ~u : (u | 0x80000000u);
}
__device__ __forceinline__ float unmapf(unsigned u){
  return __uint_as_float((u & 0x80000000u) ? (u & 0x7FFFFFFFu) : ~u);
}

__device__ float digammaf_(float x){
  float r = 0.f;
  while (x < 6.f){ r -= 1.f/x; x += 1.f; }
  float inv = 1.f/x, inv2 = inv*inv;
  r += logf(x) - 0.5f*inv
     - inv2*(0.08333333333f - inv2*(0.008333333333f - inv2*0.003968253968f));
  return r;
}

// ============ k_prep: normalize -> FRAGMENT-ORDER bf16 (fb3) + losses =======
// fb3: panel p=row/64, chunk c=k/32 (4KB each). Within a chunk, element
// (r=row%64, kk=k%32) sits at (r>>4)*512 + ((kk>>3)*16 + (r&15))*8 + (kk&7).
// => MFMA fragment mi is read by lane L at chunk + mi*512 + L*8: IDENTITY
// lane->address pattern (lane i at base + i*16B), the only pattern the HW
// coalescer turns into one transaction (round-8 lesson: dense != coalesced).
__global__ __launch_bounds__(256) void k_prep(const float* __restrict__ feat,
    __bf16* __restrict__ fb3,
    const float* __restrict__ logits, const int* __restrict__ targets,
    const float* __restrict__ alpha,  const float* __restrict__ fa,
    const float* __restrict__ cw, int B, int D,
    float* __restrict__ psum, unsigned* rowMinU, unsigned* rowMaxU,
    unsigned* done){
  int bid = blockIdx.x, tid = threadIdx.x;
  int wave = tid >> 6, lane = tid & 63;
  __shared__ float sloc[4][8];

  if (bid == 0 && tid == 0) *done = 0u;

  int row = bid*4 + wave;                       // grid = B/4, always < B
  // ---- normalize one row per wave ----
  const float* src = feat + (size_t)row*D;
  float ss = 0.f;
  for (int c = lane*4; c < D; c += 64*4){
    float4 v = *(const float4*)(src + c);
    ss += v.x*v.x + v.y*v.y + v.z*v.z + v.w*v.w;
  }
  #pragma unroll
  for (int off=32; off; off>>=1) ss += __shfl_xor(ss, off);
  float inv = 1.f / fmaxf(sqrtf(ss), 1e-12f);

  int p = row >> 6, r = row & 63;
  int fragBase = (r >> 4)*512 + (r & 15)*8;     // + cb*128 per 8-elem group
  for (int c = lane*8; c < D; c += 64*8){
    float4 v0 = *(const float4*)(src + c);
    float4 v1 = *(const float4*)(src + c + 4);
    bf8 o;
    o[0]=(__bf16)(v0.x*inv); o[1]=(__bf16)(v0.y*inv);
    o[2]=(__bf16)(v0.z*inv); o[3]=(__bf16)(v0.w*inv);
    o[4]=(__bf16)(v1.x*inv); o[5]=(__bf16)(v1.y*inv);
    o[6]=(__bf16)(v1.z*inv); o[7]=(__bf16)(v1.w*inv);
    int cc = c >> 5;                  // chunk index
    int cb = (c >> 3) & 3;            // which 8-k group within chunk
    size_t off = (size_t)(p*16 + cc)*2048 + fragBase + cb*128;
    *(bf8*)(fb3 + off) = o;
  }

  // ---- init row min/max (4 rows per block) ----
  if (tid < 4){ rowMinU[bid*4+tid] = 0xFFFFFFFFu; rowMaxU[bid*4+tid] = 0u; }

  // ---- per-sample losses: sample i = row (redundant across lanes) ----
  int i = row;
  float l0=logits[3*i], l1=logits[3*i+1], l2=logits[3*i+2];
  int t = targets[i];
  float m = fmaxf(l0, fmaxf(l1,l2));
  float e0=expf(l0-m), e1=expf(l1-m), e2=expf(l2-m);
  float se = e0+e1+e2;
  float lse = m + logf(se);
  float lp0=l0-lse, lp1=l1-lse, lp2=l2-lse;
  float lpt = (t==0)?lp0:((t==1)?lp1:lp2);
  float nll = -lpt;
  float ce_ls = 0.9f*nll + 0.1f*(-(lp0+lp1+lp2)*(1.f/3.f));
  float pt = expf(-ce_ls);
  float om = 1.f - pt;
  float focal_i = fa[t]*om*om*ce_ls;
  float w = cw[t];
  float ce_n = w*nll, ce_d = w;
  float p0=e0/se, p1=e1/se, p2=e2/se;
  float bnd;
  if (t==0)      bnd = p1 + 0.6f*p2;
  else if (t==2) bnd = p1 + 0.4f*p0;
  else           bnd = 4.5f*(1.f - p1 + 0.3f*(p0+p2));
  float a0=alpha[3*i], a1=alpha[3*i+1], a2=alpha[3*i+2];
  float S = a0+a1+a2 + 1e-8f;
  float at_ = (t==0)?a0:((t==1)?a1:a2);
  float lik = digammaf_(S) - digammaf_(at_ + 1e-8f);
  float b0 = (t==0)?1.f:a0, b1 = (t==1)?1.f:a1, b2 = (t==2)?1.f:a2;
  float ats = b0+b1+b2 + 1e-8f;
  float psa = digammaf_(ats + 1e-8f);
  float kl = lgammaf(ats)
     - (lgammaf(b0+1e-8f)+lgammaf(b1+1e-8f)+lgammaf(b2+1e-8f))
     + (b0-1.f)*(digammaf_(b0+1e-8f)-psa)
     + (b1-1.f)*(digammaf_(b1+1e-8f)-psa)
     + (b2-1.f)*(digammaf_(b2+1e-8f)-psa);
  if (lane == 0){
    sloc[wave][0]=focal_i; sloc[wave][1]=ce_n; sloc[wave][2]=ce_d;
    sloc[wave][3]=bnd;     sloc[wave][4]=lik;  sloc[wave][5]=kl;
  }
  __syncthreads();
  if (tid < 6)
    psum[bid*8+tid] = sloc[0][tid]+sloc[1][tid]+sloc[2][tid]+sloc[3][tid];
}

// ============ k_pairs: single-wave 64x64 tiles, no LDS, identity loads ======
// 2080 blocks x 64 threads, triangular (by<=bx), no barriers. Fragment loads
// are global_load_dwordx4 with lane i at base + i*16B (one transaction each);
// data lands directly in MFMA A/B operand layout (fb3 is fragment-ordered).
// Last-finishing block runs the finalize (counter + threadfence handshake).
__global__ __launch_bounds__(64) void k_pairs(const __bf16* __restrict__ fb3,
    const int* __restrict__ targets, int B, int D,
    float* __restrict__ pairPart, unsigned* rowMinU, unsigned* rowMaxU,
    unsigned* done, int nblk, int nprep,
    const float* __restrict__ psum, const int* __restrict__ epoch_p,
    float* __restrict__ out){
  // decode triangular tile index -> (by, bx), by <= bx
  int t = blockIdx.x;
  int bx = (int)((sqrtf(8.f*(float)t + 1.f) - 1.f)*0.5f);
  while ((bx+1)*(bx+2)/2 <= t) bx++;
  while (bx*(bx+1)/2 > t) bx--;
  int by = t - bx*(bx+1)/2;
  bool isDiag = (by == bx);
  int rowBase = by*64, colBase = bx*64;

  int lane = threadIdx.x;
  int quad = lane >> 4, l16 = lane & 15;
  int NCH = D/32;                                   // 16 chunks per panel

  const __bf16* pA[4]; const __bf16* pB[4];
  #pragma unroll
  for (int mi=0; mi<4; mi++){
    pA[mi] = fb3 + (size_t)by*NCH*2048 + mi*512 + lane*8;   // identity pattern
    pB[mi] = fb3 + (size_t)bx*NCH*2048 + mi*512 + lane*8;
  }

  f32x4 C[4][4] = {};
  bf8 aC[4], bC[4], aN[4], bN[4];

  #define LD(dst, P, it) do{ \
    _Pragma("unroll") \
    for (int j=0; j<4; j++) dst[j] = *(const bf8*)(P[j] + (it)*2048); \
  }while(0)

  #define COMPUTE(aF, bF) do{ \
    _Pragma("unroll") \
    for (int mi=0; mi<4; mi++) \
      _Pragma("unroll") \
      for (int ni=0; ni<4; ni++) \
        C[mi][ni] = __builtin_amdgcn_mfma_f32_16x16x32_bf16(aF[mi], bF[ni], C[mi][ni], 0,0,0); \
  }while(0)

  LD(aC, pA, 0); LD(bC, pB, 0);
  for (int it=0; it<NCH; it+=2){
    LD(aN, pA, it+1); LD(bN, pB, it+1);
    COMPUTE(aC, bC);
    if (it+2 < NCH){ LD(aC, pA, it+2); LD(bC, pB, it+2); }
    COMPUTE(aN, bN);
  }

  // ---- fused epilogue (validated rounds 1-8, absmax 0) ----
  int tcol[4];
  #pragma unroll
  for (int ni=0; ni<4; ni++) tcol[ni] = targets[colBase + ni*16 + l16];

  float pos=0.f, neg=0.f, semi=0.f, diag=0.f;
  float cmin[4], cmax[4];
  #pragma unroll
  for (int ni=0; ni<4; ni++){ cmin[ni]=2.f; cmax[ni]=-2.f; }

  #pragma unroll
  for (int mi=0; mi<4; mi++){
    #pragma unroll
    for (int r=0; r<4; r++){
      int rl = mi*16 + quad*4 + r;
      int row = rowBase + rl;
      int tr = targets[row];
      float vmin = 2.f, vmax = -2.f;
      #pragma unroll
      for (int ni=0; ni<4; ni++){
        int col = colBase + ni*16 + l16;
        float s = C[mi][ni][r];
        if (tr == tcol[ni]){
          float omv = 1.f - s;
          float q = omv*omv;
          pos += q;
          if (tr == 1) semi += q;
          if (row == col) diag += q;     // only possible on diagonal tiles
          else {
            vmin = fminf(vmin, s);
            cmin[ni] = fminf(cmin[ni], s);
          }
        } else {
          float c0 = fmaxf(s - 0.2f, 0.f);
          neg += c0*c0;
          vmax = fmaxf(vmax, s);
          cmax[ni] = fmaxf(cmax[ni], s);
        }
      }
      #pragma unroll
      for (int off=1; off<16; off<<=1){
        vmin = fminf(vmin, __shfl_xor(vmin, off));
        vmax = fmaxf(vmax, __shfl_xor(vmax, off));
      }
      if (l16 == 0){
        atomicMin(&rowMinU[row], mapf(vmin));
        atomicMax(&rowMaxU[row], mapf(vmax));
      }
    }
  }

  if (!isDiag){
    #pragma unroll
    for (int ni=0; ni<4; ni++){
      float cn = cmin[ni], cx = cmax[ni];
      cn = fminf(cn, __shfl_xor(cn, 16)); cn = fminf(cn, __shfl_xor(cn, 32));
      cx = fmaxf(cx, __shfl_xor(cx, 16)); cx = fmaxf(cx, __shfl_xor(cx, 32));
      if (quad == 0){
        int col = colBase + ni*16 + l16;
        atomicMin(&rowMinU[col], mapf(cn));
        atomicMax(&rowMaxU[col], mapf(cx));
      }
    }
  }

  #pragma unroll
  for (int off=32; off; off>>=1){
    pos  += __shfl_xor(pos, off);
    neg  += __shfl_xor(neg, off);
    semi += __shfl_xor(semi, off);
    diag += __shfl_xor(diag, off);
  }
  if (lane == 0){
    float fac = isDiag ? 1.f : 2.f;
    pairPart[blockIdx.x*4+0] = pos*fac;
    pairPart[blockIdx.x*4+1] = neg*fac;
    pairPart[blockIdx.x*4+2] = semi*fac;
    pairPart[blockIdx.x*4+3] = diag;
  }

  // ---- last-block finalize (device-scope counter handshake) ----
  __threadfence();                       // release: our stores visible
  unsigned old = 0;
  if (lane == 0) old = atomicAdd(done, 1u);
  old = (unsigned)__shfl((int)old, 0);
  if (old != (unsigned)(nblk - 1)) return;
  __threadfence();                       // acquire: everyone's stores visible

  // histogram targets
  int c0=0,c1=0,c2=0;
  for (int i4 = lane; i4 < B/4; i4 += 64){
    int4 tv = ((const int4*)targets)[i4];
    c0 += (tv.x==0)+(tv.y==0)+(tv.z==0)+(tv.w==0);
    c1 += (tv.x==1)+(tv.y==1)+(tv.z==1)+(tv.w==1);
    c2 += (tv.x==2)+(tv.y==2)+(tv.z==2)+(tv.w==2);
  }
  #pragma unroll
  for (int off=32; off; off>>=1){
    c0+=__shfl_xor(c0,off); c1+=__shfl_xor(c1,off); c2+=__shfl_xor(c2,off);
  }
  int n0=c0, n1=c1, n2=c2;

  // per-sample partials
  float v0=0,v1=0,v2=0,v3=0,v4=0,v5=0;
  for (int s = lane; s < nprep; s += 64){
    float4 a = *(const float4*)(psum + s*8);
    float4 b = *(const float4*)(psum + s*8 + 4);
    v0+=a.x; v1+=a.y; v2+=a.z; v3+=a.w; v4+=b.x; v5+=b.y;
  }
  // pair partials
  float pp=0,nn=0,ss=0,dd=0;
  for (int s = lane; s < nblk; s += 64){
    float4 a = *(const float4*)(pairPart + s*4);
    pp+=a.x; nn+=a.y; ss+=a.z; dd+=a.w;
  }
  // triplet
  float tsum = 0.f, tcnt = 0.f;
  for (int i = lane; i < B; i += 64){
    int tt = targets[i];
    int nt = (tt==0)?n0:((tt==1)?n1:n2);
    if (nt - 1 > 0 && B - nt > 0){
      float mn = unmapf(rowMinU[i]);
      float mx = unmapf(rowMaxU[i]);
      float hp = sqrtf(fmaxf(2.f - 2.f*mn, 0.f));
      float hn = sqrtf(fmaxf(2.f - 2.f*mx, 0.f));
      float margin = 1.5f * ((tt==1) ? 2.5f : 1.f);
      tsum += fmaxf(hp - hn + margin, 0.f); tcnt += 1.f;
    }
  }
  #pragma unroll
  for (int off=32; off; off>>=1){
    v0+=__shfl_xor(v0,off); v1+=__shfl_xor(v1,off); v2+=__shfl_xor(v2,off);
    v3+=__shfl_xor(v3,off); v4+=__shfl_xor(v4,off); v5+=__shfl_xor(v5,off);
    pp+=__shfl_xor(pp,off); nn+=__shfl_xor(nn,off);
    ss+=__shfl_xor(ss,off); dd+=__shfl_xor(dd,off);
    tsum+=__shfl_xor(tsum,off); tcnt+=__shfl_xor(tcnt,off);
  }
  if (lane == 0){
    float triplet = (tcnt > 0.f) ? tsum / fmaxf(tcnt, 1.f) : 0.f;
    float Bf = (float)B;
    float focal = v0 / Bf;
    float ce = v1 / v2;
    float boundary = v3 / (Bf + 1e-8f);
    float contrastive = (pp + nn + 4.f*ss) / (Bf*Bf + 1e-8f);
    long long npl = ((long long)n0*(n0-1) + (long long)n1*(n1-1) + (long long)n2*(n2-1))/2;
    float qsum = (pp - dd) * 0.5f;
    float q = qsum / (float)(npl > 0 ? npl : 1);
    if (n2 > 0) q *= (1.f + 2.5f * ((float)n2 / Bf));
    float quality = (npl > 0) ? q : 0.f;
    int ep = epoch_p[0];
    float er = (float)ep / 25.f;
    float ann = fminf(1.f, er*er);
    float evidential = v4/Bf + ann*0.2f*v5/Bf;
    float total = 0.4f*focal + 0.3f*ce + 0.15f*boundary
                + 0.1f*contrastive + 0.1f*triplet + 0.1f*quality + 0.1f*evidential;
    out[0] = total;
  }
}

extern "C" void kernel_launch(void* const* d_in, const int* in_sizes, int n_in,
                              void* d_out, int out_size, void* d_ws, size_t ws_size,
                              hipStream_t stream){
  const float* logits   = (const float*)d_in[0];
  const int*   targets  = (const int*)d_in[1];
  const float* features = (const float*)d_in[2];
  const float* alpha    = (const float*)d_in[3];
  const int*   epoch    = (const int*)d_in[4];
  const float* fa       = (const float*)d_in[5];
  const float* cw       = (const float*)d_in[6];
  int B = in_sizes[1];
  int D = in_sizes[2] / B;
  int nprep = B/4;                 // k_prep blocks == psum slots
  int T  = B / 64;
  int nblk = T*(T+1)/2;            // triangular: by <= bx

  char* ws = (char*)d_ws;
  float*    psum     = (float*)(ws);                          // nprep*8 f32 (32KB)
  unsigned* done     = (unsigned*)(ws + 49152);               // 1 u32
  float*    pairPart = (float*)(ws + 65536);                  // nblk*4 f32 (~33KB)
  unsigned* rowMinU  = (unsigned*)(ws + 131072);              // B u32
  unsigned* rowMaxU  = (unsigned*)(ws + 131072 + (size_t)B*4);
  __bf16*   fb3      = (__bf16*)(ws + 131072 + (size_t)B*8);  // B*D bf16 tiled

  k_prep <<<nprep, 256, 0, stream>>>(features, fb3, logits, targets, alpha, fa, cw,
                                     B, D, psum, rowMinU, rowMaxU, done);
  k_pairs<<<nblk, 64, 0, stream>>>(fb3, targets, B, D, pairPart, rowMinU, rowMaxU,
                                   done, nblk, nprep, psum, epoch, (float*)d_out);
}